// Round 17
// baseline (332.418 us; speedup 1.0000x reference)
//
#include <hip/hip_runtime.h>

#define N_NODES 10000
#define N_EDGES 20000
#define DIM 64
#define NF 14
#define NB 200
#define NPG 50      // nodes per graph (batch = repeat(arange(200), 50))
#define STEPS 4
#define S2S_STEPS 3

typedef short short8 __attribute__((ext_vector_type(8)));
typedef float f32x4 __attribute__((ext_vector_type(4)));
typedef unsigned short u16;

__device__ __forceinline__ u16 f2bf(float f) {
  unsigned u = __float_as_uint(f);
  u += 0x7FFFu + ((u >> 16) & 1u);   // RNE
  return (u16)(u >> 16);
}
__device__ __forceinline__ float bf2f(u16 h) {
  return __uint_as_float(((unsigned)h) << 16);
}
__device__ __forceinline__ float lrelu(float v) { return v > 0.f ? v : 0.01f * v; }
__device__ __forceinline__ float sigm(float x) { return 1.f / (1.f + expf(-x)); }

// Fused preprocessing, block-range split:
//  [0,2500):       out0 = leaky_relu(x @ lin0_w + lin0_b)             [N,64]
//  [2500,12500):   h1 = bf16(leaky_relu(edge_attr @ enet_w1 + b1))    [E,128]
//  [12500,12564):  Bt via LDS-tile transpose (coalesced read & write)
//  [12564,12628):  b2p, wihT, whhT
//  [12628,12707):  cnti = int scatter-count of dst (for CSR)
// We column permutation: stored col c = i8*512 + o*8 + kx maps to weight
// element (i = i8*8+kx, o), so k_msg's wave (lane=o) reads 1KB contiguous
// chunks per i8.  Bt[c][k'] = w2[k'][ (i8*8+kx)*64 + o ].
__global__ __launch_bounds__(256) void k_prep_all(
    const float* __restrict__ x, const float* __restrict__ lin0_w,
    const float* __restrict__ lin0_b, float* __restrict__ out0,
    const float* __restrict__ ea, const float* __restrict__ w1,
    const float* __restrict__ b1, u16* __restrict__ h1,
    const float* __restrict__ w2, const float* __restrict__ b2,
    const float* __restrict__ wih, const float* __restrict__ whh,
    u16* __restrict__ Bt, float* __restrict__ b2p,
    float* __restrict__ wihT, float* __restrict__ whhT,
    const int* __restrict__ dst, int* __restrict__ cnti) {
  const int b = blockIdx.x, tid = threadIdx.x;
  if (b < 2500) {                      // lin0: 2500*256 = N*64 exact
    int t = b * 256 + tid;
    int n = t >> 6, o = t & 63;
    float acc = lin0_b[o];
    #pragma unroll
    for (int f = 0; f < NF; ++f) acc += x[n * NF + f] * lin0_w[f * DIM + o];
    out0[t] = lrelu(acc);
  } else if (b < 12500) {              // h1: 10000*256 = E*128 exact
    int t = (b - 2500) * 256 + tid;
    int e = t >> 7, k = t & 127;
    float acc = b1[k];
    #pragma unroll
    for (int f = 0; f < 4; ++f) acc += ea[e * 4 + f] * w1[f * 128 + k];
    h1[t] = f2bf(lrelu(acc));
  } else if (b < 12564) {              // Bt transpose: 64 blocks, one (i8,kx)
    __shared__ float tile[128][65];    // +1 pad
    int pb = b - 12500;
    int i8 = pb >> 3, kx = pb & 7;
    int col0 = (i8 * 8 + kx) * 64;
    #pragma unroll
    for (int rep = 0; rep < 32; ++rep) {
      int idx = rep * 256 + tid;       // 8192 = 128k * 64o
      int k = idx >> 6, o = idx & 63;
      tile[k][o] = w2[(size_t)k * 4096 + col0 + o];   // coalesced rows
    }
    __syncthreads();
    int o = tid >> 2, kq = (tid & 3) * 32;
    size_t c = (size_t)i8 * 512 + o * 8 + kx;
    u16* dstp8 = Bt + c * 128 + kq;
    #pragma unroll
    for (int j = 0; j < 32; ++j) dstp8[j] = f2bf(tile[kq + j][o]);
  } else if (b < 12628) {              // b2p + GRU weight transposes
    int t = (b - 12564) * 256 + tid;
    if (t < 4096) {
      int iw = (t >> 9) * 8 + (t & 7);
      int ow = (t >> 3) & 63;
      b2p[t] = b2[iw * 64 + ow];
    }
    if (t < 3 * 64 * 64) {
      int p = t >> 12, rem = t & 4095, i = rem >> 6, o = rem & 63;
      int g = p * 64 + o;
      wihT[t] = wih[g * 64 + i];
      whhT[t] = whh[g * 64 + i];
    }
  } else {                             // cnti
    int t = (b - 12628) * 256 + tid;
    if (t < N_EDGES) atomicAdd(cnti + dst[t], 1);
  }
}

// k_scan: single-block exclusive scan of cnti -> row_ptr[0..N_NODES].
// Wave-shfl scans (verified R10/R11/R16).
__global__ __launch_bounds__(256) void k_scan(const int* __restrict__ tot,
                                              int* __restrict__ row_ptr) {
  __shared__ int s_ws[4];
  __shared__ int carry;
  const int tid = threadIdx.x;
  const int lane = tid & 63, wv = tid >> 6;
  if (tid == 0) carry = 0;
  __syncthreads();
  for (int base = 0; base < N_NODES; base += 256) {
    int v = (base + tid < N_NODES) ? tot[base + tid] : 0;
    int x = v;
    #pragma unroll
    for (int off = 1; off < 64; off <<= 1) {
      int y = __shfl_up(x, off, 64);
      if (lane >= off) x += y;
    }
    if (lane == 63) s_ws[wv] = x;
    __syncthreads();
    int woff = 0;
    #pragma unroll
    for (int w = 0; w < 4; ++w) woff += (w < wv) ? s_ws[w] : 0;
    if (base + tid < N_NODES) row_ptr[base + tid] = carry + woff + x - v;
    int ctot = s_ws[0] + s_ws[1] + s_ws[2] + s_ws[3];
    __syncthreads();
    if (tid == 0) carry += ctot;
    __syncthreads();
  }
  if (tid == 0) row_ptr[N_NODES] = carry;
}

// k_fill: csr_pos[e] = slot of edge e in dst-sorted order. Slot order within
// a node is nondeterministic but the SET is exact; node-sum is an f32 add
// (order noise ~1e-7 << 1.3e-3 threshold).
__global__ __launch_bounds__(256) void k_fill(const int* __restrict__ dst,
    const int* __restrict__ row_ptr, int* __restrict__ fillc,
    int* __restrict__ csr_pos) {
  int e = blockIdx.x * 256 + threadIdx.x;
  if (e >= N_EDGES) return;
  int n = dst[e];
  int slot = atomicAdd(fillc + n, 1);
  csr_pos[e] = row_ptr[n] + slot;
}

// We = h1 @ Bt^T + b2p   M=20000 N=4096 K=128, bf16 in/out, f32 accum.
// (unchanged from R15 — 46 us, write-BW-bound)
__global__ __launch_bounds__(256, 3) void k_gemm(const u16* __restrict__ A,
    const u16* __restrict__ Bt, const float* __restrict__ bias,
    u16* __restrict__ C) {
  __shared__ __align__(16) u16 smem[128 * 136];   // 34.8 KB
  u16* As = smem;
  const int tid = threadIdx.x;
  const int n0 = blockIdx.x * 128;   // 32 n-tiles, fastest -> XCD-pinned B
  const int m0 = blockIdx.y * 128;   // 157 m-stripes
  const int lane = tid & 63;
  const int wv = tid >> 6;
  const int lo = lane & 15;
  const int hi = lane >> 4;
  short8 st[8];
  #pragma unroll
  for (int it = 0; it < 8; ++it) {
    int chunk = it * 256 + tid;
    int r = chunk >> 4;
    int g = (chunk & 15) ^ (r & 7);          // pre-swizzled source granule
    st[it] = *(const short8*)(A + (size_t)(m0 + r) * 128 + g * 8);
  }
  const u16* brow0 = Bt + ((size_t)n0 + wv * 32 + lo) * 128;
  const u16* brow1 = brow0 + 16 * 128;
  short8 bq0[4], bq1[4];
  #pragma unroll
  for (int kk = 0; kk < 4; ++kk) {
    const int kof = kk * 32 + hi * 8;
    bq0[kk] = *(const short8*)(brow0 + kof);
    bq1[kk] = *(const short8*)(brow1 + kof);
  }
  #pragma unroll
  for (int it = 0; it < 8; ++it)
    *(short8*)(As + ((size_t)it * 256 + tid) * 8) = st[it];   // linear write
  __syncthreads();
  f32x4 acc[8][2];
  #pragma unroll
  for (int mf = 0; mf < 8; ++mf) {
    acc[mf][0] = (f32x4){0.f, 0.f, 0.f, 0.f};
    acc[mf][1] = (f32x4){0.f, 0.f, 0.f, 0.f};
  }
  #pragma unroll
  for (int kk = 0; kk < 4; ++kk) {
    const int gsr = ((kk * 4 + hi) ^ (lo & 7)) * 8;   // row&7 == lo&7
    #pragma unroll
    for (int mf = 0; mf < 8; ++mf) {
      short8 a = *(const short8*)(As + (mf * 16 + lo) * 128 + gsr);
      acc[mf][0] = __builtin_amdgcn_mfma_f32_16x16x32_bf16(bq0[kk], a, acc[mf][0], 0, 0, 0);
      acc[mf][1] = __builtin_amdgcn_mfma_f32_16x16x32_bf16(bq1[kk], a, acc[mf][1], 0, 0, 0);
    }
  }
  const int nsL = wv * 32 + hi * 4;
  f32x4 bv0 = *(const f32x4*)(bias + n0 + nsL);
  f32x4 bv1 = *(const f32x4*)(bias + n0 + nsL + 16);
  __syncthreads();
  u16* Cs = smem;
  #pragma unroll
  for (int mf = 0; mf < 8; ++mf) {
    int lrow = mf * 16 + lo;
    uint2 p0, p1;
    p0.x = (unsigned)f2bf(acc[mf][0][0] + bv0[0]) |
           ((unsigned)f2bf(acc[mf][0][1] + bv0[1]) << 16);
    p0.y = (unsigned)f2bf(acc[mf][0][2] + bv0[2]) |
           ((unsigned)f2bf(acc[mf][0][3] + bv0[3]) << 16);
    *(uint2*)(Cs + lrow * 136 + nsL) = p0;
    p1.x = (unsigned)f2bf(acc[mf][1][0] + bv1[0]) |
           ((unsigned)f2bf(acc[mf][1][1] + bv1[1]) << 16);
    p1.y = (unsigned)f2bf(acc[mf][1][2] + bv1[2]) |
           ((unsigned)f2bf(acc[mf][1][3] + bv1[3]) << 16);
    *(uint2*)(Cs + lrow * 136 + nsL + 16) = p1;
  }
  __syncthreads();
  #pragma unroll
  for (int it = 0; it < 8; ++it) {
    int chunk = it * 256 + tid;
    int row = chunk >> 4;
    int c8 = (chunk & 15) * 8;
    int grow = m0 + row;
    if (grow < N_EDGES)
      *(short8*)(C + (size_t)grow * 4096 + n0 + c8) =
          *(const short8*)(Cs + row * 136 + c8);
  }
}

// msg[e,o] = sum_i out[src[e],i] * We_perm; SEQUENTIAL We stream (edge =
// block order, perfectly coalesced). T14 async-split: all 8 loads issued
// BEFORE the out-gather + barrier. NO atomics: plain 256B store to the
// edge's CSR slot; k_node sums contiguous slot runs.
__global__ __launch_bounds__(256) void k_msg(const u16* __restrict__ We,
    const float* __restrict__ out, const int* __restrict__ src,
    const int* __restrict__ csr_pos, float* __restrict__ msgbuf) {
  __shared__ float s_o[4][64];
  const int w = threadIdx.x >> 6, o = threadIdx.x & 63;
  const int e = blockIdx.x * 4 + w;          // grid exact: 5000*4 = 20000
  const u16* wp = We + (size_t)e * 4096 + o * 8;
  short8 w0 = *(const short8*)(wp);
  short8 w1 = *(const short8*)(wp + 512);
  short8 w2 = *(const short8*)(wp + 1024);
  short8 w3 = *(const short8*)(wp + 1536);
  short8 w4 = *(const short8*)(wp + 2048);
  short8 w5 = *(const short8*)(wp + 2560);
  short8 w6 = *(const short8*)(wp + 3072);
  short8 w7 = *(const short8*)(wp + 3584);
  const int s = __builtin_amdgcn_readfirstlane(src[e]);
  const int pos = __builtin_amdgcn_readfirstlane(csr_pos[e]);
  s_o[w][o] = out[(size_t)s * 64 + o];
  __syncthreads();
  float acc = 0.f;
#define MSG_GROUP(WV, J)                                                  \
  {                                                                       \
    f32x4 o0 = *(const f32x4*)(&s_o[w][(J) * 8]);                         \
    f32x4 o1 = *(const f32x4*)(&s_o[w][(J) * 8 + 4]);                     \
    acc += bf2f((u16)WV[0]) * o0[0] + bf2f((u16)WV[1]) * o0[1]            \
         + bf2f((u16)WV[2]) * o0[2] + bf2f((u16)WV[3]) * o0[3]            \
         + bf2f((u16)WV[4]) * o1[0] + bf2f((u16)WV[5]) * o1[1]            \
         + bf2f((u16)WV[6]) * o1[2] + bf2f((u16)WV[7]) * o1[3];           \
  }
  MSG_GROUP(w0, 0)
  MSG_GROUP(w1, 1)
  MSG_GROUP(w2, 2)
  MSG_GROUP(w3, 3)
  MSG_GROUP(w4, 4)
  MSG_GROUP(w5, 5)
  MSG_GROUP(w6, 6)
  MSG_GROUP(w7, 7)
#undef MSG_GROUP
  msgbuf[(size_t)pos * 64 + o] = acc;
}

// Node update: TWO nodes per wave, lane = output dim.
// agg = sum of contiguous msgbuf slots [row_ptr[n], row_ptr[n+1]) (L2-hit);
// m = lrelu(agg/deg + out@conv_root + cbias); GRU(h=out) -> out_next.
__global__ __launch_bounds__(256) void k_node(
    const float* __restrict__ msgbuf, const int* __restrict__ row_ptr,
    const float* __restrict__ out_cur,
    const float* __restrict__ cr,        // conv_root [i][o], o contiguous
    const float* __restrict__ cbias,
    const float* __restrict__ wihT, const float* __restrict__ whhT,
    const float* __restrict__ bih, const float* __restrict__ bhh,
    float* __restrict__ out_next) {
  __shared__ float s_h[4][2][64];
  __shared__ float s_m[4][2][64];
  const int w = threadIdx.x >> 6, o = threadIdx.x & 63;
  const int nd0 = blockIdx.x * 8 + w * 2;     // 1250 blocks * 8 = 10000 exact
  const int nd1 = nd0 + 1;
  const int rb0 = row_ptr[nd0], re0 = row_ptr[nd0 + 1], re1 = row_ptr[nd1 + 1];
  const float hv0 = out_cur[(size_t)nd0 * 64 + o];
  const float hv1 = out_cur[(size_t)nd1 * 64 + o];
  s_h[w][0][o] = hv0;
  s_h[w][1][o] = hv1;
  float g0 = 0.f, g1 = 0.f;
  for (int j = rb0; j < re0; ++j) g0 += msgbuf[(size_t)j * 64 + o];
  for (int j = re0; j < re1; ++j) g1 += msgbuf[(size_t)j * 64 + o];
  float a0 = g0 / (float)max(re0 - rb0, 1) + cbias[o];
  float a1 = g1 / (float)max(re1 - re0, 1) + cbias[o];
  __syncthreads();
  #pragma unroll 4
  for (int i = 0; i < 64; ++i) {
    float cv = cr[i * 64 + o];
    a0 += s_h[w][0][i] * cv;
    a1 += s_h[w][1][i] * cv;
  }
  s_m[w][0][o] = lrelu(a0);
  s_m[w][1][o] = lrelu(a1);
  __syncthreads();
  float gi0a = bih[o],       gh0a = bhh[o];
  float gi1a = bih[64 + o],  gh1a = bhh[64 + o];
  float gi2a = bih[128 + o], gh2a = bhh[128 + o];
  float gi0b = gi0a, gh0b = gh0a, gi1b = gi1a, gh1b = gh1a, gi2b = gi2a, gh2b = gh2a;
  #pragma unroll 4
  for (int i = 0; i < 64; ++i) {
    int io = i * 64 + o;
    float wi0 = wihT[io], wi1 = wihT[4096 + io], wi2 = wihT[8192 + io];
    float wh0 = whhT[io], wh1 = whhT[4096 + io], wh2 = whhT[8192 + io];
    float m0v = s_m[w][0][i], hva = s_h[w][0][i];
    float m1v = s_m[w][1][i], hvb = s_h[w][1][i];
    gi0a += m0v * wi0; gh0a += hva * wh0;
    gi1a += m0v * wi1; gh1a += hva * wh1;
    gi2a += m0v * wi2; gh2a += hva * wh2;
    gi0b += m1v * wi0; gh0b += hvb * wh0;
    gi1b += m1v * wi1; gh1b += hvb * wh1;
    gi2b += m1v * wi2; gh2b += hvb * wh2;
  }
  {
    float r_ = sigm(gi0a + gh0a);
    float z_ = sigm(gi1a + gh1a);
    float cand = tanhf(gi2a + r_ * gh2a);
    out_next[(size_t)nd0 * 64 + o] = (1.f - z_) * cand + z_ * hv0;
  }
  {
    float r_ = sigm(gi0b + gh0b);
    float z_ = sigm(gi1b + gh1b);
    float cand = tanhf(gi2b + r_ * gh2b);
    out_next[(size_t)nd1 * 64 + o] = (1.f - z_) * cand + z_ * hv1;
  }
}

// Set2Set + final linear: one block per graph (50 contiguous nodes).
__global__ __launch_bounds__(256) void k_s2s(const float* __restrict__ out,
    const float* __restrict__ wih, const float* __restrict__ whh,
    const float* __restrict__ bih, const float* __restrict__ bhh,
    const float* __restrict__ l1w, const float* __restrict__ l1b,
    float* __restrict__ dout) {
  __shared__ float s_out[NPG * 64];
  __shared__ float s_q[128];
  __shared__ float s_hs[64];
  __shared__ float s_cs[64];
  __shared__ float s_g[256];
  __shared__ float s_e[64];
  __shared__ float s_a[64];
  __shared__ float s_r[4][64];
  const int gb = blockIdx.x, tid = threadIdx.x;
  for (int t = tid; t < NPG * 64; t += 256)
    s_out[t] = out[(size_t)gb * NPG * 64 + t];
  if (tid < 128) s_q[tid] = 0.f;
  if (tid < 64) { s_hs[tid] = 0.f; s_cs[tid] = 0.f; }
  __syncthreads();
  for (int it = 0; it < S2S_STEPS; ++it) {
    float acc = bih[tid] + bhh[tid];
    const float* wi = wih + tid * 128;
    #pragma unroll 8
    for (int j = 0; j < 128; ++j) acc += s_q[j] * wi[j];
    const float* wh = whh + tid * 64;
    #pragma unroll 8
    for (int j = 0; j < 64; ++j) acc += s_hs[j] * wh[j];
    s_g[tid] = acc;
    __syncthreads();
    if (tid < 64) {
      float i_ = s_g[tid], f_ = s_g[64 + tid], g_ = s_g[128 + tid], o_ = s_g[192 + tid];
      float cs = sigm(f_) * s_cs[tid] + sigm(i_) * tanhf(g_);
      s_cs[tid] = cs;
      s_hs[tid] = sigm(o_) * tanhf(cs);
    }
    __syncthreads();
    {
      int wvi = tid >> 6, ln = tid & 63;
      for (int node = wvi; node < NPG; node += 4) {
        float p = s_out[node * 64 + ln] * s_hs[ln];
        #pragma unroll
        for (int m = 32; m; m >>= 1) p += __shfl_xor(p, m, 64);
        if (ln == 0) s_e[node] = p;
      }
    }
    __syncthreads();
    if (tid < 64) {
      float e = (tid < NPG) ? s_e[tid] : -1e30f;
      float mx = e;
      #pragma unroll
      for (int m = 32; m; m >>= 1) mx = fmaxf(mx, __shfl_xor(mx, m, 64));
      float a = (tid < NPG) ? expf(e - mx) : 0.f;
      float su = a;
      #pragma unroll
      for (int m = 32; m; m >>= 1) su += __shfl_xor(su, m, 64);
      s_a[tid] = a / su;
    }
    __syncthreads();
    {
      int wvi = tid >> 6, ln = tid & 63;
      float r = 0.f;
      for (int n2 = wvi; n2 < NPG; n2 += 4) r += s_a[n2] * s_out[n2 * 64 + ln];
      s_r[wvi][ln] = r;
    }
    __syncthreads();
    if (tid < 64) {
      s_q[64 + tid] = s_r[0][tid] + s_r[1][tid] + s_r[2][tid] + s_r[3][tid];
      s_q[tid] = s_hs[tid];
    }
    __syncthreads();
  }
  if (tid < 128) s_g[tid] = s_q[tid] * l1w[tid];
  __syncthreads();
  if (tid == 0) {
    float sm = 0.f;
    for (int j = 0; j < 128; ++j) sm += s_g[j];
    dout[gb] = sm + l1b[0];
  }
}

extern "C" void kernel_launch(void* const* d_in, const int* in_sizes, int n_in,
                              void* d_out, int out_size, void* d_ws, size_t ws_size,
                              hipStream_t stream) {
  (void)in_sizes; (void)n_in; (void)out_size; (void)ws_size;
  const float* x         = (const float*)d_in[0];
  const float* edge_attr = (const float*)d_in[1];
  const float* lin0_w    = (const float*)d_in[2];
  const float* lin0_b    = (const float*)d_in[3];
  const float* enet_w1   = (const float*)d_in[4];
  const float* enet_b1   = (const float*)d_in[5];
  const float* enet_w2   = (const float*)d_in[6];
  const float* enet_b2   = (const float*)d_in[7];
  const float* conv_root = (const float*)d_in[8];
  const float* conv_bias = (const float*)d_in[9];
  const float* gru_w_ih  = (const float*)d_in[10];
  const float* gru_w_hh  = (const float*)d_in[11];
  const float* gru_b_ih  = (const float*)d_in[12];
  const float* gru_b_hh  = (const float*)d_in[13];
  const float* s2s_w_ih  = (const float*)d_in[14];
  const float* s2s_w_hh  = (const float*)d_in[15];
  const float* s2s_b_ih  = (const float*)d_in[16];
  const float* s2s_b_hh  = (const float*)d_in[17];
  const float* lin1_w    = (const float*)d_in[18];
  const float* lin1_b    = (const float*)d_in[19];
  const int* edge_index  = (const int*)d_in[20];
  const int* srcp = edge_index;
  const int* dstp = edge_index + N_EDGES;

  char* ws = (char*)d_ws;
  size_t off = 0;
  auto carve = [&](size_t bytes) -> void* {
    void* p = ws + off;
    off += (bytes + 255) & ~(size_t)255;
    return p;
  };
  u16*   We      = (u16*)carve((size_t)N_EDGES * 4096 * 2);   // 163.84 MB
  u16*   h1      = (u16*)carve((size_t)20096 * 128 * 2);      // padded rows
  u16*   Bt      = (u16*)carve((size_t)4096 * 128 * 2);       // 1 MB
  float* b2p     = (float*)carve(4096 * 4);
  float* wihT    = (float*)carve(3 * 64 * 64 * 4);
  float* whhT    = (float*)carve(3 * 64 * 64 * 4);
  float* out_a   = (float*)carve((size_t)N_NODES * 64 * 4);
  float* out_b   = (float*)carve((size_t)N_NODES * 64 * 4);
  float* msgbuf  = (float*)carve((size_t)N_EDGES * 64 * 4);   // 5.12 MB
  int*   cnti    = (int*)carve(N_NODES * 4);
  int*   fillc   = (int*)carve(N_NODES * 4);
  int*   row_ptr = (int*)carve((N_NODES + 1) * 4);
  int*   csr_pos = (int*)carve(N_EDGES * 4);

  hipMemsetAsync(cnti, 0, N_NODES * 4, stream);
  hipMemsetAsync(fillc, 0, N_NODES * 4, stream);
  k_prep_all<<<12707, 256, 0, stream>>>(
      x, lin0_w, lin0_b, out_a,
      edge_attr, enet_w1, enet_b1, h1,
      enet_w2, enet_b2, gru_w_ih, gru_w_hh, Bt, b2p, wihT, whhT,
      dstp, cnti);
  k_scan<<<1, 256, 0, stream>>>(cnti, row_ptr);
  k_fill<<<(N_EDGES + 255) / 256, 256, 0, stream>>>(dstp, row_ptr, fillc, csr_pos);
  dim3 gg(4096 / 128, (N_EDGES + 127) / 128);   // n fastest: XCD pins B-tiles
  k_gemm<<<gg, 256, 0, stream>>>(h1, Bt, b2p, We);

  float* cur = out_a;
  float* nxt = out_b;
  for (int s = 0; s < STEPS; ++s) {
    k_msg<<<N_EDGES / 4, 256, 0, stream>>>(We, cur, srcp, csr_pos, msgbuf);
    k_node<<<N_NODES / 8, 256, 0, stream>>>(msgbuf, row_ptr, cur,
        conv_root, conv_bias, wihT, whhT, gru_b_ih, gru_b_hh, nxt);
    float* t = cur; cur = nxt; nxt = t;
  }
  k_s2s<<<NB, 256, 0, stream>>>(cur, s2s_w_ih, s2s_w_hh, s2s_b_ih, s2s_b_hh,
      lin1_w, lin1_b, (float*)d_out);
}

// Round 18
// 295.276 us; speedup vs baseline: 1.1258x; 1.1258x over previous
//
#include <hip/hip_runtime.h>

#define N_NODES 10000
#define N_EDGES 20000
#define DIM 64
#define NF 14
#define NB 200
#define NPG 50      // nodes per graph (batch = repeat(arange(200), 50))
#define STEPS 4
#define S2S_STEPS 3

typedef short short8 __attribute__((ext_vector_type(8)));
typedef float f32x4 __attribute__((ext_vector_type(4)));
typedef unsigned short u16;

__device__ __forceinline__ u16 f2bf(float f) {
  unsigned u = __float_as_uint(f);
  u += 0x7FFFu + ((u >> 16) & 1u);   // RNE
  return (u16)(u >> 16);
}
__device__ __forceinline__ float bf2f(u16 h) {
  return __uint_as_float(((unsigned)h) << 16);
}
__device__ __forceinline__ float lrelu(float v) { return v > 0.f ? v : 0.01f * v; }
__device__ __forceinline__ float sigm(float x) { return 1.f / (1.f + expf(-x)); }

// Fused preprocessing, block-range split:
//  [0,2500):       out0 = leaky_relu(x @ lin0_w + lin0_b)             [N,64]
//  [2500,12500):   h1 = bf16(leaky_relu(edge_attr @ enet_w1 + b1))    [E,128]
//  [12500,12564):  Bt via LDS-tile transpose (coalesced read & write)
//  [12564,12628):  b2p, wihT, whhT
//  [12628,12707):  cnt = scatter-count of dst
// We column permutation: stored col c = i8*512 + o*8 + kx maps to weight
// element (i = i8*8+kx, o), so k_msg's wave (lane=o) reads 1KB contiguous
// chunks per i8.  Bt[c][k'] = w2[k'][ (i8*8+kx)*64 + o ].
__global__ __launch_bounds__(256) void k_prep_all(
    const float* __restrict__ x, const float* __restrict__ lin0_w,
    const float* __restrict__ lin0_b, float* __restrict__ out0,
    const float* __restrict__ ea, const float* __restrict__ w1,
    const float* __restrict__ b1, u16* __restrict__ h1,
    const float* __restrict__ w2, const float* __restrict__ b2,
    const float* __restrict__ wih, const float* __restrict__ whh,
    u16* __restrict__ Bt, float* __restrict__ b2p,
    float* __restrict__ wihT, float* __restrict__ whhT,
    const int* __restrict__ dst, float* __restrict__ cnt) {
  const int b = blockIdx.x, tid = threadIdx.x;
  if (b < 2500) {                      // lin0: 2500*256 = N*64 exact
    int t = b * 256 + tid;
    int n = t >> 6, o = t & 63;
    float acc = lin0_b[o];
    #pragma unroll
    for (int f = 0; f < NF; ++f) acc += x[n * NF + f] * lin0_w[f * DIM + o];
    out0[t] = lrelu(acc);
  } else if (b < 12500) {              // h1: 10000*256 = E*128 exact
    int t = (b - 2500) * 256 + tid;
    int e = t >> 7, k = t & 127;
    float acc = b1[k];
    #pragma unroll
    for (int f = 0; f < 4; ++f) acc += ea[e * 4 + f] * w1[f * 128 + k];
    h1[t] = f2bf(lrelu(acc));
  } else if (b < 12564) {              // Bt transpose: 64 blocks, one (i8,kx)
    __shared__ float tile[128][65];    // +1 pad
    int pb = b - 12500;
    int i8 = pb >> 3, kx = pb & 7;
    int col0 = (i8 * 8 + kx) * 64;
    #pragma unroll
    for (int rep = 0; rep < 32; ++rep) {
      int idx = rep * 256 + tid;       // 8192 = 128k * 64o
      int k = idx >> 6, o = idx & 63;
      tile[k][o] = w2[(size_t)k * 4096 + col0 + o];   // coalesced rows
    }
    __syncthreads();
    int o = tid >> 2, kq = (tid & 3) * 32;
    size_t c = (size_t)i8 * 512 + o * 8 + kx;
    u16* dstp8 = Bt + c * 128 + kq;
    #pragma unroll
    for (int j = 0; j < 32; ++j) dstp8[j] = f2bf(tile[kq + j][o]);
  } else if (b < 12628) {              // b2p + GRU weight transposes
    int t = (b - 12564) * 256 + tid;
    if (t < 4096) {
      int iw = (t >> 9) * 8 + (t & 7);
      int ow = (t >> 3) & 63;
      b2p[t] = b2[iw * 64 + ow];
    }
    if (t < 3 * 64 * 64) {
      int p = t >> 12, rem = t & 4095, i = rem >> 6, o = rem & 63;
      int g = p * 64 + o;
      wihT[t] = wih[g * 64 + i];
      whhT[t] = whh[g * 64 + i];
    }
  } else {                             // cnt
    int t = (b - 12628) * 256 + tid;
    if (t < N_EDGES) atomicAdd(cnt + dst[t], 1.f);
  }
}

// We = h1 @ Bt^T + b2p   M=20000 N=4096 K=128, bf16 in/out, f32 accum.
// Hybrid: A staged in LDS (pre-swizzled global source -> linear LDS write;
// read slot (kk*4+hi)^(lo&7) since row&7==lo&7), B preloaded into registers
// from global (L2-resident via n-fastest grid -> XCD-pinned B). mfma(b,a)
// computes C^T. Epilogue: repack C-tile via LDS (stride 136 u16, 16B-aligned)
// -> coalesced 16B short8 stores (full write-combine sectors).
__global__ __launch_bounds__(256, 3) void k_gemm(const u16* __restrict__ A,
    const u16* __restrict__ Bt, const float* __restrict__ bias,
    u16* __restrict__ C) {
  __shared__ __align__(16) u16 smem[128 * 136];   // 34.8 KB; As uses first 32 KB
  u16* As = smem;
  const int tid = threadIdx.x;
  const int n0 = blockIdx.x * 128;   // 32 n-tiles, fastest -> XCD-pinned B
  const int m0 = blockIdx.y * 128;   // 157 m-stripes
  const int lane = tid & 63;
  const int wv = tid >> 6;
  const int lo = lane & 15;
  const int hi = lane >> 4;

  // --- stage full A-tile: 2048 chunks of 16B, 8 per thread ---
  // A is padded to 20096 rows so the last stripe reads in-bounds garbage.
  short8 st[8];
  #pragma unroll
  for (int it = 0; it < 8; ++it) {
    int chunk = it * 256 + tid;              // 0..2047
    int r = chunk >> 4;                      // 0..127
    int g = (chunk & 15) ^ (r & 7);          // pre-swizzled source granule
    st[it] = *(const short8*)(A + (size_t)(m0 + r) * 128 + g * 8);
  }
  // --- preload B fragments (8 x 16B per lane) while A-loads fly ---
  const u16* brow0 = Bt + ((size_t)n0 + wv * 32 + lo) * 128;
  const u16* brow1 = brow0 + 16 * 128;
  short8 bq0[4], bq1[4];
  #pragma unroll
  for (int kk = 0; kk < 4; ++kk) {
    const int kof = kk * 32 + hi * 8;
    bq0[kk] = *(const short8*)(brow0 + kof);
    bq1[kk] = *(const short8*)(brow1 + kof);
  }
  #pragma unroll
  for (int it = 0; it < 8; ++it)
    *(short8*)(As + ((size_t)it * 256 + tid) * 8) = st[it];   // linear write
  __syncthreads();

  f32x4 acc[8][2];
  #pragma unroll
  for (int mf = 0; mf < 8; ++mf) {
    acc[mf][0] = (f32x4){0.f, 0.f, 0.f, 0.f};
    acc[mf][1] = (f32x4){0.f, 0.f, 0.f, 0.f};
  }
  #pragma unroll
  for (int kk = 0; kk < 4; ++kk) {
    const int gsr = ((kk * 4 + hi) ^ (lo & 7)) * 8;   // row&7 == lo&7
    #pragma unroll
    for (int mf = 0; mf < 8; ++mf) {
      short8 a = *(const short8*)(As + (mf * 16 + lo) * 128 + gsr);
      acc[mf][0] = __builtin_amdgcn_mfma_f32_16x16x32_bf16(bq0[kk], a, acc[mf][0], 0, 0, 0);
      acc[mf][1] = __builtin_amdgcn_mfma_f32_16x16x32_bf16(bq1[kk], a, acc[mf][1], 0, 0, 0);
    }
  }
  // C^T layout: lane (lo,hi) reg r = C[m0+mf*16+lo][n0+wv*32+nf*16+hi*4+r]
  const int nsL = wv * 32 + hi * 4;     // local col base
  f32x4 bv0 = *(const f32x4*)(bias + n0 + nsL);
  f32x4 bv1 = *(const f32x4*)(bias + n0 + nsL + 16);
  __syncthreads();   // all waves done reading As; reuse smem as Cs
  u16* Cs = smem;    // [128 rows][136 u16] (stride 272 B, 16B-aligned)
  #pragma unroll
  for (int mf = 0; mf < 8; ++mf) {
    int lrow = mf * 16 + lo;
    uint2 p0, p1;
    p0.x = (unsigned)f2bf(acc[mf][0][0] + bv0[0]) |
           ((unsigned)f2bf(acc[mf][0][1] + bv0[1]) << 16);
    p0.y = (unsigned)f2bf(acc[mf][0][2] + bv0[2]) |
           ((unsigned)f2bf(acc[mf][0][3] + bv0[3]) << 16);
    *(uint2*)(Cs + lrow * 136 + nsL) = p0;
    p1.x = (unsigned)f2bf(acc[mf][1][0] + bv1[0]) |
           ((unsigned)f2bf(acc[mf][1][1] + bv1[1]) << 16);
    p1.y = (unsigned)f2bf(acc[mf][1][2] + bv1[2]) |
           ((unsigned)f2bf(acc[mf][1][3] + bv1[3]) << 16);
    *(uint2*)(Cs + lrow * 136 + nsL + 16) = p1;
  }
  __syncthreads();
  #pragma unroll
  for (int it = 0; it < 8; ++it) {
    int chunk = it * 256 + tid;
    int row = chunk >> 4;
    int c8 = (chunk & 15) * 8;
    int grow = m0 + row;
    if (grow < N_EDGES)
      *(short8*)(C + (size_t)grow * 4096 + n0 + c8) =
          *(const short8*)(Cs + row * 136 + c8);
  }
}

// msg[e,o] = sum_i out[src[e],i] * We_perm; perfectly coalesced We stream.
// Wave = edge, lane = o. T14 async-split: all 8 loads issued BEFORE the
// out-gather + barrier. Plain (cacheable) loads: We (164 MB) fits L3.
__global__ __launch_bounds__(256) void k_msg(const u16* __restrict__ We,
    const float* __restrict__ out, const int* __restrict__ src,
    const int* __restrict__ dst, float* __restrict__ agg) {
  __shared__ float s_o[4][64];
  const int w = threadIdx.x >> 6, o = threadIdx.x & 63;
  const int e = blockIdx.x * 4 + w;          // grid exact: 5000*4 = 20000
  const u16* wp = We + (size_t)e * 4096 + o * 8;
  short8 w0 = *(const short8*)(wp);
  short8 w1 = *(const short8*)(wp + 512);
  short8 w2 = *(const short8*)(wp + 1024);
  short8 w3 = *(const short8*)(wp + 1536);
  short8 w4 = *(const short8*)(wp + 2048);
  short8 w5 = *(const short8*)(wp + 2560);
  short8 w6 = *(const short8*)(wp + 3072);
  short8 w7 = *(const short8*)(wp + 3584);
  const int s = __builtin_amdgcn_readfirstlane(src[e]);
  const int d = __builtin_amdgcn_readfirstlane(dst[e]);
  s_o[w][o] = out[(size_t)s * 64 + o];
  __syncthreads();
  float acc = 0.f;
#define MSG_GROUP(WV, J)                                                  \
  {                                                                       \
    f32x4 o0 = *(const f32x4*)(&s_o[w][(J) * 8]);                         \
    f32x4 o1 = *(const f32x4*)(&s_o[w][(J) * 8 + 4]);                     \
    acc += bf2f((u16)WV[0]) * o0[0] + bf2f((u16)WV[1]) * o0[1]            \
         + bf2f((u16)WV[2]) * o0[2] + bf2f((u16)WV[3]) * o0[3]            \
         + bf2f((u16)WV[4]) * o1[0] + bf2f((u16)WV[5]) * o1[1]            \
         + bf2f((u16)WV[6]) * o1[2] + bf2f((u16)WV[7]) * o1[3];           \
  }
  MSG_GROUP(w0, 0)
  MSG_GROUP(w1, 1)
  MSG_GROUP(w2, 2)
  MSG_GROUP(w3, 3)
  MSG_GROUP(w4, 4)
  MSG_GROUP(w5, 5)
  MSG_GROUP(w6, 6)
  MSG_GROUP(w7, 7)
#undef MSG_GROUP
  atomicAdd(agg + (size_t)d * 64 + o, acc);
}

// Node update: TWO nodes per wave (halves per-node weight traffic),
// lane = output dim.  m = lrelu(agg/denom + out@conv_root + cbias);
// GRU(h=out) -> out_next.  Re-zeroes agg for the next step.
__global__ __launch_bounds__(256) void k_node(float* __restrict__ agg,
    const float* __restrict__ cnt, const float* __restrict__ out_cur,
    const float* __restrict__ cr,        // conv_root [i][o], o contiguous
    const float* __restrict__ cbias,
    const float* __restrict__ wihT, const float* __restrict__ whhT,
    const float* __restrict__ bih, const float* __restrict__ bhh,
    float* __restrict__ out_next) {
  __shared__ float s_h[4][2][64];
  __shared__ float s_m[4][2][64];
  const int w = threadIdx.x >> 6, o = threadIdx.x & 63;
  const int nd0 = blockIdx.x * 8 + w * 2;     // 1250 blocks * 8 = 10000 exact
  const int nd1 = nd0 + 1;
  const float hv0 = out_cur[(size_t)nd0 * 64 + o];
  const float hv1 = out_cur[(size_t)nd1 * 64 + o];
  s_h[w][0][o] = hv0;
  s_h[w][1][o] = hv1;
  float a0 = agg[(size_t)nd0 * 64 + o] / fmaxf(cnt[nd0], 1.f) + cbias[o];
  float a1 = agg[(size_t)nd1 * 64 + o] / fmaxf(cnt[nd1], 1.f) + cbias[o];
  agg[(size_t)nd0 * 64 + o] = 0.f;
  agg[(size_t)nd1 * 64 + o] = 0.f;
  __syncthreads();
  #pragma unroll 4
  for (int i = 0; i < 64; ++i) {
    float cv = cr[i * 64 + o];
    a0 += s_h[w][0][i] * cv;
    a1 += s_h[w][1][i] * cv;
  }
  s_m[w][0][o] = lrelu(a0);
  s_m[w][1][o] = lrelu(a1);
  __syncthreads();
  float gi0a = bih[o],       gh0a = bhh[o];
  float gi1a = bih[64 + o],  gh1a = bhh[64 + o];
  float gi2a = bih[128 + o], gh2a = bhh[128 + o];
  float gi0b = gi0a, gh0b = gh0a, gi1b = gi1a, gh1b = gh1a, gi2b = gi2a, gh2b = gh2a;
  #pragma unroll 4
  for (int i = 0; i < 64; ++i) {
    int io = i * 64 + o;
    float wi0 = wihT[io], wi1 = wihT[4096 + io], wi2 = wihT[8192 + io];
    float wh0 = whhT[io], wh1 = whhT[4096 + io], wh2 = whhT[8192 + io];
    float m0v = s_m[w][0][i], hva = s_h[w][0][i];
    float m1v = s_m[w][1][i], hvb = s_h[w][1][i];
    gi0a += m0v * wi0; gh0a += hva * wh0;
    gi1a += m0v * wi1; gh1a += hva * wh1;
    gi2a += m0v * wi2; gh2a += hva * wh2;
    gi0b += m1v * wi0; gh0b += hvb * wh0;
    gi1b += m1v * wi1; gh1b += hvb * wh1;
    gi2b += m1v * wi2; gh2b += hvb * wh2;
  }
  {
    float r_ = sigm(gi0a + gh0a);
    float z_ = sigm(gi1a + gh1a);
    float cand = tanhf(gi2a + r_ * gh2a);
    out_next[(size_t)nd0 * 64 + o] = (1.f - z_) * cand + z_ * hv0;
  }
  {
    float r_ = sigm(gi0b + gh0b);
    float z_ = sigm(gi1b + gh1b);
    float cand = tanhf(gi2b + r_ * gh2b);
    out_next[(size_t)nd1 * 64 + o] = (1.f - z_) * cand + z_ * hv1;
  }
}

// Set2Set + final linear: one block per graph (50 contiguous nodes).
__global__ __launch_bounds__(256) void k_s2s(const float* __restrict__ out,
    const float* __restrict__ wih, const float* __restrict__ whh,
    const float* __restrict__ bih, const float* __restrict__ bhh,
    const float* __restrict__ l1w, const float* __restrict__ l1b,
    float* __restrict__ dout) {
  __shared__ float s_out[NPG * 64];
  __shared__ float s_q[128];
  __shared__ float s_hs[64];
  __shared__ float s_cs[64];
  __shared__ float s_g[256];
  __shared__ float s_e[64];
  __shared__ float s_a[64];
  __shared__ float s_r[4][64];
  const int gb = blockIdx.x, tid = threadIdx.x;
  for (int t = tid; t < NPG * 64; t += 256)
    s_out[t] = out[(size_t)gb * NPG * 64 + t];
  if (tid < 128) s_q[tid] = 0.f;
  if (tid < 64) { s_hs[tid] = 0.f; s_cs[tid] = 0.f; }
  __syncthreads();
  for (int it = 0; it < S2S_STEPS; ++it) {
    float acc = bih[tid] + bhh[tid];
    const float* wi = wih + tid * 128;
    #pragma unroll 8
    for (int j = 0; j < 128; ++j) acc += s_q[j] * wi[j];
    const float* wh = whh + tid * 64;
    #pragma unroll 8
    for (int j = 0; j < 64; ++j) acc += s_hs[j] * wh[j];
    s_g[tid] = acc;
    __syncthreads();
    if (tid < 64) {
      float i_ = s_g[tid], f_ = s_g[64 + tid], g_ = s_g[128 + tid], o_ = s_g[192 + tid];
      float cs = sigm(f_) * s_cs[tid] + sigm(i_) * tanhf(g_);
      s_cs[tid] = cs;
      s_hs[tid] = sigm(o_) * tanhf(cs);
    }
    __syncthreads();
    {
      int wvi = tid >> 6, ln = tid & 63;
      for (int node = wvi; node < NPG; node += 4) {
        float p = s_out[node * 64 + ln] * s_hs[ln];
        #pragma unroll
        for (int m = 32; m; m >>= 1) p += __shfl_xor(p, m, 64);
        if (ln == 0) s_e[node] = p;
      }
    }
    __syncthreads();
    if (tid < 64) {
      float e = (tid < NPG) ? s_e[tid] : -1e30f;
      float mx = e;
      #pragma unroll
      for (int m = 32; m; m >>= 1) mx = fmaxf(mx, __shfl_xor(mx, m, 64));
      float a = (tid < NPG) ? expf(e - mx) : 0.f;
      float su = a;
      #pragma unroll
      for (int m = 32; m; m >>= 1) su += __shfl_xor(su, m, 64);
      s_a[tid] = a / su;
    }
    __syncthreads();
    {
      int wvi = tid >> 6, ln = tid & 63;
      float r = 0.f;
      for (int n2 = wvi; n2 < NPG; n2 += 4) r += s_a[n2] * s_out[n2 * 64 + ln];
      s_r[wvi][ln] = r;
    }
    __syncthreads();
    if (tid < 64) {
      s_q[64 + tid] = s_r[0][tid] + s_r[1][tid] + s_r[2][tid] + s_r[3][tid];
      s_q[tid] = s_hs[tid];
    }
    __syncthreads();
  }
  if (tid < 128) s_g[tid] = s_q[tid] * l1w[tid];
  __syncthreads();
  if (tid == 0) {
    float sm = 0.f;
    for (int j = 0; j < 128; ++j) sm += s_g[j];
    dout[gb] = sm + l1b[0];
  }
}

extern "C" void kernel_launch(void* const* d_in, const int* in_sizes, int n_in,
                              void* d_out, int out_size, void* d_ws, size_t ws_size,
                              hipStream_t stream) {
  (void)in_sizes; (void)n_in; (void)out_size; (void)ws_size;
  const float* x         = (const float*)d_in[0];
  const float* edge_attr = (const float*)d_in[1];
  const float* lin0_w    = (const float*)d_in[2];
  const float* lin0_b    = (const float*)d_in[3];
  const float* enet_w1   = (const float*)d_in[4];
  const float* enet_b1   = (const float*)d_in[5];
  const float* enet_w2   = (const float*)d_in[6];
  const float* enet_b2   = (const float*)d_in[7];
  const float* conv_root = (const float*)d_in[8];
  const float* conv_bias = (const float*)d_in[9];
  const float* gru_w_ih  = (const float*)d_in[10];
  const float* gru_w_hh  = (const float*)d_in[11];
  const float* gru_b_ih  = (const float*)d_in[12];
  const float* gru_b_hh  = (const float*)d_in[13];
  const float* s2s_w_ih  = (const float*)d_in[14];
  const float* s2s_w_hh  = (const float*)d_in[15];
  const float* s2s_b_ih  = (const float*)d_in[16];
  const float* s2s_b_hh  = (const float*)d_in[17];
  const float* lin1_w    = (const float*)d_in[18];
  const float* lin1_b    = (const float*)d_in[19];
  const int* edge_index  = (const int*)d_in[20];
  const int* srcp = edge_index;
  const int* dstp = edge_index + N_EDGES;

  char* ws = (char*)d_ws;
  size_t off = 0;
  auto carve = [&](size_t bytes) -> void* {
    void* p = ws + off;
    off += (bytes + 255) & ~(size_t)255;
    return p;
  };
  u16*   We    = (u16*)carve((size_t)N_EDGES * 4096 * 2);   // 163.84 MB
  u16*   h1    = (u16*)carve((size_t)20096 * 128 * 2);      // padded to 157*128 rows
  u16*   Bt    = (u16*)carve((size_t)4096 * 128 * 2);       // 1 MB
  float* b2p   = (float*)carve(4096 * 4);
  float* wihT  = (float*)carve(3 * 64 * 64 * 4);
  float* whhT  = (float*)carve(3 * 64 * 64 * 4);
  float* out_a = (float*)carve((size_t)N_NODES * 64 * 4);
  float* out_b = (float*)carve((size_t)N_NODES * 64 * 4);
  float* aggb  = (float*)carve((size_t)N_NODES * 64 * 4);
  float* cnt   = (float*)carve(N_NODES * 4);

  hipMemsetAsync(cnt, 0, N_NODES * 4, stream);
  hipMemsetAsync(aggb, 0, (size_t)N_NODES * 64 * 4, stream);
  k_prep_all<<<12707, 256, 0, stream>>>(
      x, lin0_w, lin0_b, out_a,
      edge_attr, enet_w1, enet_b1, h1,
      enet_w2, enet_b2, gru_w_ih, gru_w_hh, Bt, b2p, wihT, whhT,
      dstp, cnt);
  dim3 gg(4096 / 128, (N_EDGES + 127) / 128);   // n fastest: XCD pins B-tiles
  k_gemm<<<gg, 256, 0, stream>>>(h1, Bt, b2p, We);

  float* cur = out_a;
  float* nxt = out_b;
  for (int s = 0; s < STEPS; ++s) {
    k_msg<<<N_EDGES / 4, 256, 0, stream>>>(We, cur, srcp, dstp, aggb);
    k_node<<<N_NODES / 8, 256, 0, stream>>>(aggb, cnt, cur, conv_root, conv_bias,
        wihT, whhT, gru_b_ih, gru_b_hh, nxt);
    float* t = cur; cur = nxt; nxt = t;
  }
  k_s2s<<<NB, 256, 0, stream>>>(cur, s2s_w_ih, s2s_w_hh, s2s_b_ih, s2s_b_hh,
      lin1_w, lin1_b, (float*)d_out);
}